// Round 1
// baseline (126.221 us; speedup 1.0000x reference)
//
#include <hip/hip_runtime.h>

// SNN forward scan: per spatial position, sequential over T=16 timesteps.
//   a1 = sigmoid(alpha_1)-0.5, b1 = sigmoid(beta_1)-0.5
//   a2 = sigmoid(alpha_2)+0.5, b2 = sigmoid(beta_2)+0.5
//   v_d = a1*v_d + b1*v_s + x_t
//   v_s = a2*v_s + b2*v_d
//   out = (v_s - vth >= 0) ? vth : 0 ;  v_s -= out
// Purely elementwise across N = B*C*H*W positions -> state in registers,
// float4-vectorized coalesced loads/stores. Memory-bound.

#define T_STEPS 16

__global__ __launch_bounds__(256) void LMH_90254442758290_kernel(
    const float4* __restrict__ x, float4* __restrict__ out,
    const float* __restrict__ p_a1, const float* __restrict__ p_b1,
    const float* __restrict__ p_a2, const float* __restrict__ p_b2,
    const float* __restrict__ p_vth, long n4)
{
    // Broadcast scalars (L2/L1-cached single-element reads; compute once per thread)
    const float a1 = 1.0f / (1.0f + expf(-p_a1[0])) - 0.5f;
    const float b1 = 1.0f / (1.0f + expf(-p_b1[0])) - 0.5f;
    const float a2 = 1.0f / (1.0f + expf(-p_a2[0])) + 0.5f;
    const float b2 = 1.0f / (1.0f + expf(-p_b2[0])) + 0.5f;
    const float vth = p_vth[0];

    const long stride = (long)gridDim.x * blockDim.x;
    for (long i = (long)blockIdx.x * blockDim.x + threadIdx.x; i < n4; i += stride) {
        float vd[4] = {0.0f, 0.0f, 0.0f, 0.0f};
        float vs[4];
#pragma unroll
        for (int k = 0; k < 4; ++k) vs[k] = 0.5f * vth;

        for (int t = 0; t < T_STEPS; ++t) {
            float4 xt = x[(long)t * n4 + i];
            float xa[4] = {xt.x, xt.y, xt.z, xt.w};
            float oa[4];
#pragma unroll
            for (int k = 0; k < 4; ++k) {
                vd[k] = a1 * vd[k] + b1 * vs[k] + xa[k];
                vs[k] = a2 * vs[k] + b2 * vd[k];
                float o = (vs[k] - vth >= 0.0f) ? vth : 0.0f;
                vs[k] -= o;
                oa[k] = o;
            }
            out[(long)t * n4 + i] = make_float4(oa[0], oa[1], oa[2], oa[3]);
        }
    }
}

extern "C" void kernel_launch(void* const* d_in, const int* in_sizes, int n_in,
                              void* d_out, int out_size, void* d_ws, size_t ws_size,
                              hipStream_t stream) {
    const float* x    = (const float*)d_in[0];
    const float* a1   = (const float*)d_in[1];
    const float* b1   = (const float*)d_in[2];
    const float* a2   = (const float*)d_in[3];
    const float* b2   = (const float*)d_in[4];
    const float* vth  = (const float*)d_in[5];
    float* out        = (float*)d_out;

    const long total = (long)in_sizes[0];       // T*B*C*H*W
    const long n     = total / T_STEPS;         // per-timestep elements (divisible)
    const long n4    = n / 4;                   // float4 elements per timestep

    const int block = 256;
    long want = (n4 + block - 1) / block;
    int grid = (int)(want < 2048 ? want : 2048);  // grid-stride covers the rest

    LMH_90254442758290_kernel<<<grid, block, 0, stream>>>(
        (const float4*)x, (float4*)out, a1, b1, a2, b2, vth, n4);
}

// Round 3
// 118.867 us; speedup vs baseline: 1.0619x; 1.0619x over previous
//
#include <hip/hip_runtime.h>

// SNN forward scan: per spatial position, sequential over T=16 timesteps.
//   a1 = sigmoid(alpha_1)-0.5, b1 = sigmoid(beta_1)-0.5
//   a2 = sigmoid(alpha_2)+0.5, b2 = sigmoid(beta_2)+0.5
//   v_d = a1*v_d + b1*v_s + x_t
//   v_s = a2*v_s + b2*v_d
//   out = (v_s - vth >= 0) ? vth : 0 ;  v_s -= out
//
// Purely elementwise across N = B*C*H*W positions. T fully unrolled:
// 16 nontemporal float4 loads issued up front (MLP=16/thread), state chain
// in registers, 16 nontemporal stores. Streaming traffic, no cache reuse.
// NOTE: __builtin_nontemporal_* needs a clang vector type, not HIP float4.

#define T_STEPS 16

typedef float f32x4 __attribute__((ext_vector_type(4)));

__global__ __launch_bounds__(256) void LMH_90254442758290_kernel(
    const f32x4* __restrict__ x, f32x4* __restrict__ out,
    const float* __restrict__ p_a1, const float* __restrict__ p_b1,
    const float* __restrict__ p_a2, const float* __restrict__ p_b2,
    const float* __restrict__ p_vth, long n4)
{
    const float a1 = 1.0f / (1.0f + expf(-p_a1[0])) - 0.5f;
    const float b1 = 1.0f / (1.0f + expf(-p_b1[0])) - 0.5f;
    const float a2 = 1.0f / (1.0f + expf(-p_a2[0])) + 0.5f;
    const float b2 = 1.0f / (1.0f + expf(-p_b2[0])) + 0.5f;
    const float vth = p_vth[0];

    const long i = (long)blockIdx.x * blockDim.x + threadIdx.x;
    if (i >= n4) return;

    // Issue all 16 loads before any use: 16 outstanding VMEM ops per thread.
    f32x4 xt[T_STEPS];
#pragma unroll
    for (int t = 0; t < T_STEPS; ++t)
        xt[t] = __builtin_nontemporal_load(&x[(long)t * n4 + i]);

    f32x4 vd = {0.0f, 0.0f, 0.0f, 0.0f};
    f32x4 vs = {0.5f * vth, 0.5f * vth, 0.5f * vth, 0.5f * vth};

#pragma unroll
    for (int t = 0; t < T_STEPS; ++t) {
        f32x4 o;
#pragma unroll
        for (int k = 0; k < 4; ++k) {
            vd[k] = a1 * vd[k] + b1 * vs[k] + xt[t][k];
            vs[k] = a2 * vs[k] + b2 * vd[k];
            float ok = (vs[k] - vth >= 0.0f) ? vth : 0.0f;
            vs[k] -= ok;
            o[k] = ok;
        }
        xt[t] = o;  // reuse regs for output
    }

#pragma unroll
    for (int t = 0; t < T_STEPS; ++t)
        __builtin_nontemporal_store(xt[t], &out[(long)t * n4 + i]);
}

extern "C" void kernel_launch(void* const* d_in, const int* in_sizes, int n_in,
                              void* d_out, int out_size, void* d_ws, size_t ws_size,
                              hipStream_t stream) {
    const float* x    = (const float*)d_in[0];
    const float* a1   = (const float*)d_in[1];
    const float* b1   = (const float*)d_in[2];
    const float* a2   = (const float*)d_in[3];
    const float* b2   = (const float*)d_in[4];
    const float* vth  = (const float*)d_in[5];
    float* out        = (float*)d_out;

    const long total = (long)in_sizes[0];       // T*B*C*H*W
    const long n     = total / T_STEPS;         // per-timestep elements
    const long n4    = n / 4;                   // float4 elements per timestep

    const int block = 256;
    const int grid  = (int)((n4 + block - 1) / block);  // one float4 per thread

    LMH_90254442758290_kernel<<<grid, block, 0, stream>>>(
        (const f32x4*)x, (f32x4*)out, a1, b1, a2, b2, vth, n4);
}

// Round 4
// 85.341 us; speedup vs baseline: 1.4790x; 1.3928x over previous
//
#include <hip/hip_runtime.h>

// SNN forward scan: per spatial position, sequential over T=16 timesteps.
//   a1 = sigmoid(alpha_1)-0.5, b1 = sigmoid(beta_1)-0.5
//   a2 = sigmoid(alpha_2)+0.5, b2 = sigmoid(beta_2)+0.5
//   v_d = a1*v_d + b1*v_s + x_t
//   v_s = a2*v_s + b2*v_d
//   out = (v_s - vth >= 0) ? vth : 0 ;  v_s -= out
//
// Memory-bound elementwise scan. Key cache play: x (268 MB) nearly fits the
// 256 MB Infinity Cache and is re-read every graph replay -> let loads
// ALLOCATE normally (L3 residency across replays). The output has zero reuse
// -> NON-TEMPORAL stores so 268 MB of writes don't evict x from L3.

#define T_STEPS 16

typedef float f32x4 __attribute__((ext_vector_type(4)));

__global__ __launch_bounds__(256) void LMH_90254442758290_kernel(
    const f32x4* __restrict__ x, f32x4* __restrict__ out,
    const float* __restrict__ p_a1, const float* __restrict__ p_b1,
    const float* __restrict__ p_a2, const float* __restrict__ p_b2,
    const float* __restrict__ p_vth, long n4)
{
    const float a1 = 1.0f / (1.0f + expf(-p_a1[0])) - 0.5f;
    const float b1 = 1.0f / (1.0f + expf(-p_b1[0])) - 0.5f;
    const float a2 = 1.0f / (1.0f + expf(-p_a2[0])) + 0.5f;
    const float b2 = 1.0f / (1.0f + expf(-p_b2[0])) + 0.5f;
    const float vth = p_vth[0];

    const long i = (long)blockIdx.x * blockDim.x + threadIdx.x;
    if (i >= n4) return;

    // Issue all 16 loads before any use (MLP). Normal cached loads: allow
    // x to allocate in L2/L3 so subsequent graph replays hit the MALL.
    f32x4 xt[T_STEPS];
#pragma unroll
    for (int t = 0; t < T_STEPS; ++t)
        xt[t] = x[(long)t * n4 + i];

    f32x4 vd = {0.0f, 0.0f, 0.0f, 0.0f};
    f32x4 vs = {0.5f * vth, 0.5f * vth, 0.5f * vth, 0.5f * vth};

#pragma unroll
    for (int t = 0; t < T_STEPS; ++t) {
        f32x4 o;
#pragma unroll
        for (int k = 0; k < 4; ++k) {
            vd[k] = a1 * vd[k] + b1 * vs[k] + xt[t][k];
            vs[k] = a2 * vs[k] + b2 * vd[k];
            float ok = (vs[k] - vth >= 0.0f) ? vth : 0.0f;
            vs[k] -= ok;
            o[k] = ok;
        }
        xt[t] = o;  // reuse regs for output
    }

    // Non-temporal stores: no L2/L3 allocation -> don't evict x.
#pragma unroll
    for (int t = 0; t < T_STEPS; ++t)
        __builtin_nontemporal_store(xt[t], &out[(long)t * n4 + i]);
}

extern "C" void kernel_launch(void* const* d_in, const int* in_sizes, int n_in,
                              void* d_out, int out_size, void* d_ws, size_t ws_size,
                              hipStream_t stream) {
    const float* x    = (const float*)d_in[0];
    const float* a1   = (const float*)d_in[1];
    const float* b1   = (const float*)d_in[2];
    const float* a2   = (const float*)d_in[3];
    const float* b2   = (const float*)d_in[4];
    const float* vth  = (const float*)d_in[5];
    float* out        = (float*)d_out;

    const long total = (long)in_sizes[0];       // T*B*C*H*W
    const long n     = total / T_STEPS;         // per-timestep elements
    const long n4    = n / 4;                   // float4 elements per timestep

    const int block = 256;
    const int grid  = (int)((n4 + block - 1) / block);  // one float4 per thread

    LMH_90254442758290_kernel<<<grid, block, 0, stream>>>(
        (const f32x4*)x, (f32x4*)out, a1, b1, a2, b2, vth, n4);
}